// Round 11
// baseline (75.063 us; speedup 1.0000x reference)
//
#include <hip/hip_runtime.h>
#include <hip/hip_fp16.h>

// Joint bilateral filter block — 5-wave cooperative, thread-per-patch,
// row-aligned fp16 LDS tile, slab-aligned task split (wave w = z-slab w).
// x (1,1,20,96,96) f32; guide_im (N,343) f32, N = 16*96*96 = 147456;
// out n = dd*9216 + h*96 + w uses x depths dd+1..dd+3, H/W zero-pad.
//
// History: r4 52.5 (4xb32 rows, 4 waves); r9 51.4 (b128 rows, 4 waves);
// r10 fdot2 regressed 56.0 (packed weights -> VGPR arrays, not SGPR).
// r5-r8 (8-wave / persistent / reg-prefetch) all regressed (spill/lockstep).
// This round: TPB=320, 5 slab-aligned waves -> 15 waves/CU (3 LDS-bound
// blocks x 5), 105 rows/patch, sparse f32 partials in the aliased union.

#define NPATCH 147456
#define TPB     320        // 5 waves
#define PPB      64        // patches per block (one per lane, all waves share)
#define NBLK   (NPATCH / PPB)   // 2304
#define ROW_H     8        // halves per row: 7 data + 1 pad (16 B aligned)
#define PATCH_H 392        // 49 rows * 8 halves = 784 B per patch
#define PATCH_D 196        // dwords per patch
#define NF4    5488        // float4s per 64-patch tile (64*343/4)

// ---------------- Kernel A: domain branch (runs once, 1 block) --------------
__global__ __launch_bounds__(128) void domain_branch_kernel(
    const float* __restrict__ dn,
    const float* __restrict__ w1, const float* __restrict__ b1,
    const float* __restrict__ w2, const float* __restrict__ b2,
    float* __restrict__ dom_out)
{
    __shared__ float s_in[344];
    __shared__ float s_c1[128];
    const int t = threadIdx.x;
    for (int idx = t; idx < 343; idx += 128) s_in[idx] = dn[idx];
    __syncthreads();
    if (t < 125) {
        const int i = t / 25, j = (t / 5) % 5, k = t % 5;
        float acc = b1[0];
        const float* base = &s_in[i * 49 + j * 7 + k];
#pragma unroll
        for (int dz = 0; dz < 3; ++dz)
#pragma unroll
            for (int dy = 0; dy < 3; ++dy)
#pragma unroll
                for (int dx = 0; dx < 3; ++dx)
                    acc = fmaf(base[dz * 49 + dy * 7 + dx], w1[dz * 9 + dy * 3 + dx], acc);
        s_c1[t] = fmaxf(acc, 0.f);
    }
    __syncthreads();
    if (t < 27) {
        const int dz = t / 9, dy = (t / 3) % 3, dx = t % 3;
        float acc = b2[0];
#pragma unroll
        for (int u = 0; u < 3; ++u)
#pragma unroll
            for (int v = 0; v < 3; ++v)
#pragma unroll
                for (int q = 0; q < 3; ++q)
                    acc = fmaf(s_c1[(dz + u) * 25 + (dy + v) * 5 + (dx + q)],
                               w2[u * 9 + v * 3 + q], acc);
        dom_out[t] = fmaxf(acc, 0.f);
    }
}

// ---------------- helpers ----------------
__device__ __forceinline__ float h2f_lo(unsigned int q) {
    return __half2float(__ushort_as_half((unsigned short)(q & 0xffffu)));
}
__device__ __forceinline__ float h2f_hi(unsigned int q) {
    return __half2float(__ushort_as_half((unsigned short)(q >> 16)));
}
__device__ __forceinline__ unsigned short f2h(float f) {
    return __half_as_ushort(__float2half(f));
}

// Load row y of absolute z-slice zi (16B-aligned, 8-half rows) into d[0..6].
// One ds_read_b128. zi, y fold to compile-time constants after unrolling.
__device__ __forceinline__ void load_row(const unsigned int* __restrict__ P, float* d,
                                         int zi, int y) {
    const int d0 = zi * 28 + y * 4;        // dword offset, multiple of 4 -> 16B
    const uint4 q = *reinterpret_cast<const uint4*>(P + d0);
    d[0] = h2f_lo(q.x); d[1] = h2f_hi(q.x);
    d[2] = h2f_lo(q.y); d[3] = h2f_hi(q.y);
    d[4] = h2f_lo(q.z); d[5] = h2f_hi(q.z);
    d[6] = h2f_lo(q.w);
}

// Run conv1+fused-conv2 row-tasks for one z-slab i = I (j = 0..4),
// accumulating into a2 (partial: only dz2 reachable from I are touched).
template<int I>
__device__ __forceinline__ void run_slab(const unsigned int* __restrict__ P,
                                         const float* __restrict__ w1, float bb1,
                                         const float* __restrict__ w2,
                                         float (&a2)[3][3][3])
{
    float rw[3][3][7];                        // [u][y%3][k]
#pragma unroll
    for (int j = 0; j <= 4; ++j) {
        if (j == 0) {
#pragma unroll
            for (int u = 0; u < 3; ++u)
#pragma unroll
                for (int dy = 0; dy < 3; ++dy)
                    load_row(P, rw[u][dy], I + u, dy);
        } else {
#pragma unroll
            for (int u = 0; u < 3; ++u)
                load_row(P, rw[u][(j + 2) % 3], I + u, j + 2);
        }

        // c1 row (I, j, k=0..4)
        float c1r[5];
#pragma unroll
        for (int k = 0; k < 5; ++k) {
            float a = bb1;
#pragma unroll
            for (int u = 0; u < 3; ++u)
#pragma unroll
                for (int v = 0; v < 3; ++v) {
                    const float* rr = rw[u][(j + v) % 3];
#pragma unroll
                    for (int w = 0; w < 3; ++w)
                        a = fmaf(rr[k + w], w1[u * 9 + v * 3 + w], a);
                }
            c1r[k] = fmaxf(a, 0.f);
        }

        // fused conv2 accumulation
#pragma unroll
        for (int dz2 = 0; dz2 < 3; ++dz2) {
            const int u2 = I - dz2;
            if (u2 >= 0 && u2 < 3) {
#pragma unroll
                for (int v2 = 0; v2 < 3; ++v2) {
                    const int dy2 = j - v2;
                    if (dy2 >= 0 && dy2 < 3) {
#pragma unroll
                        for (int dx2 = 0; dx2 < 3; ++dx2)
#pragma unroll
                            for (int q = 0; q < 3; ++q)
                                a2[dz2][dy2][dx2] =
                                    fmaf(c1r[dx2 + q],
                                         w2[u2 * 9 + v2 * 3 + q],
                                         a2[dz2][dy2][dx2]);
                    }
                }
            }
        }
    }
}

// ---------------- Kernel B: range branch + bilateral combine ----------------
__global__ __launch_bounds__(TPB, 3) void jbf_main_kernel(
    const float* __restrict__ guide, const float* __restrict__ x,
    const float* __restrict__ w1, const float* __restrict__ b1,
    const float* __restrict__ w2, const float* __restrict__ b2,
    const float* __restrict__ dom, float* __restrict__ out)
{
    // partials buffer aliases the (dead-by-then) patch tile: 50,176 B total
    // sparse layout per lane (73-pad -> conflict-free):
    //   [0..17]  wave1 (i=1): dz2=0,1
    //   [18..44] wave2 (i=2): dz2=0,1,2
    //   [45..62] wave3 (i=3): dz2=1,2
    //   [63..71] wave4 (i=4): dz2=2
    union SM {
        unsigned short tile[PPB * PATCH_H];   // 50,176 B
        float part[PPB][73];                  // 18,688 B
    };
    __shared__ SM sm;

    const int tid  = threadIdx.x;
    const int wid  = tid >> 6;      // wave 0..4
    const int lane = tid & 63;      // patch owned by this thread
    const int blk  = blockIdx.x;

    // ============== stage 64 patches (21952 f32, contiguous) -> fp16 LDS ===
    // element (p, e) -> row r = e/7, x = e%7; dst = p*392 + r*8 + x
    const float4* __restrict__ src =
        reinterpret_cast<const float4*>(guide + (size_t)blk * (PPB * 343));

#define STORE4(IT, C) do {                                       \
        int flat = (IT) * (TPB * 4) + tid * 4;                   \
        int p    = flat / 343;                                   \
        int e    = flat - p * 343;                               \
        int r    = e / 7;                                        \
        int xx_  = e - r * 7;                                    \
        int dst  = p * PATCH_H + r * ROW_H + xx_;                \
        float v4[4] = {(C).x, (C).y, (C).z, (C).w};              \
        _Pragma("unroll")                                        \
        for (int el = 0; el < 4; ++el) {                         \
            sm.tile[dst] = f2h(v4[el]);                          \
            ++dst; if (++xx_ == 7) { xx_ = 0; ++dst; }           \
        }                                                        \
    } while (0)

    {
        float4 buf[4];
#pragma unroll
        for (int k = 0; k < 4; ++k) buf[k] = src[k * TPB + tid];

#pragma unroll 1
        for (int it0 = 0; it0 < 16; it0 += 4) {     // processes rounds 0..15
#pragma unroll
            for (int k = 0; k < 4; ++k) {
                float4 cur = buf[k];
                int idx = (it0 + 4 + k) * TPB + tid;
                if (idx > NF4 - 1) idx = NF4 - 1;   // clamp (safe dup load)
                buf[k] = src[idx];
                STORE4(it0 + k, cur);
            }
        }
        STORE4(16, buf[0]);                 // round 16: 5120+tid < 5488, valid
        if (tid < 48) STORE4(17, buf[1]);   // round 17 partial: 5440+tid < 5488
    }
#undef STORE4
    __syncthreads();

    // ===================== per-thread conv1+conv2 (slab per wave) ===========
    const unsigned int* __restrict__ P =
        reinterpret_cast<const unsigned int*>(sm.tile) + lane * PATCH_D;
    const float bb1 = b1[0];

    float a2[3][3][3];
    {
        const float init = (wid == 0) ? b2[0] : 0.f;   // bias added exactly once
#pragma unroll
        for (int a = 0; a < 3; ++a)
#pragma unroll
            for (int b = 0; b < 3; ++b)
#pragma unroll
                for (int c = 0; c < 3; ++c) a2[a][b][c] = init;
    }

    if      (wid == 0) run_slab<0>(P, w1, bb1, w2, a2);
    else if (wid == 1) run_slab<1>(P, w1, bb1, w2, a2);
    else if (wid == 2) run_slab<2>(P, w1, bb1, w2, a2);
    else if (wid == 3) run_slab<3>(P, w1, bb1, w2, a2);
    else               run_slab<4>(P, w1, bb1, w2, a2);

    __syncthreads();     // all tile reads complete before aliasing as `part`

    if (wid == 1) {          // dz2 = 0,1
#pragma unroll
        for (int dz = 0; dz < 2; ++dz)
#pragma unroll
            for (int q = 0; q < 9; ++q)
                sm.part[lane][dz * 9 + q] = a2[dz][q / 3][q % 3];
    } else if (wid == 2) {   // dz2 = 0,1,2
#pragma unroll
        for (int dz = 0; dz < 3; ++dz)
#pragma unroll
            for (int q = 0; q < 9; ++q)
                sm.part[lane][18 + dz * 9 + q] = a2[dz][q / 3][q % 3];
    } else if (wid == 3) {   // dz2 = 1,2
#pragma unroll
        for (int dz = 1; dz < 3; ++dz)
#pragma unroll
            for (int q = 0; q < 9; ++q)
                sm.part[lane][45 + (dz - 1) * 9 + q] = a2[dz][q / 3][q % 3];
    } else if (wid == 4) {   // dz2 = 2
#pragma unroll
        for (int q = 0; q < 9; ++q)
            sm.part[lane][63 + q] = a2[2][q / 3][q % 3];
    }
    __syncthreads();

    // ===================== combine + bilateral (wave 0 only) ================
    if (wid == 0) {
        const int n   = blk * PPB + lane;
        const int dd  = n / 9216;
        const int rem = n - dd * 9216;
        const int h   = rem / 96;
        const int w_  = rem - h * 96;

        float num = 0.f, den = 0.f;
#pragma unroll
        for (int dz = 0; dz < 3; ++dz)
#pragma unroll
            for (int dy = 0; dy < 3; ++dy)
#pragma unroll
                for (int dx = 0; dx < 3; ++dx) {
                    const int t9 = dy * 3 + dx;
                    float r2 = a2[dz][dy][dx];                    // wave0 + bias
                    if (dz < 2)  r2 += sm.part[lane][dz * 9 + t9];        // w1
                    r2 += sm.part[lane][18 + dz * 9 + t9];                // w2
                    if (dz >= 1) r2 += sm.part[lane][45 + (dz - 1) * 9 + t9]; // w3
                    if (dz == 2) r2 += sm.part[lane][63 + t9];            // w4
                    r2 = fmaxf(r2, 0.f);
                    const float wt = fmaf(dom[dz * 9 + t9], r2, 1e-10f);
                    const int yy = h - 1 + dy, xx = w_ - 1 + dx;
                    float xv = 0.f;
                    if (yy >= 0 && yy < 96 && xx >= 0 && xx < 96)
                        xv = x[(dd + 1 + dz) * 9216 + yy * 96 + xx];
                    num = fmaf(wt, xv, num);
                    den += wt;
                }
        out[n] = num / den;
    }
}

extern "C" void kernel_launch(void* const* d_in, const int* in_sizes, int n_in,
                              void* d_out, int out_size, void* d_ws, size_t ws_size,
                              hipStream_t stream) {
    const float* x     = (const float*)d_in[0];
    const float* dn    = (const float*)d_in[1];
    const float* guide = (const float*)d_in[2];
    const float* w1_d  = (const float*)d_in[3];
    const float* b1_d  = (const float*)d_in[4];
    const float* w2_d  = (const float*)d_in[5];
    const float* b2_d  = (const float*)d_in[6];
    const float* w1_r  = (const float*)d_in[7];
    const float* b1_r  = (const float*)d_in[8];
    const float* w2_r  = (const float*)d_in[9];
    const float* b2_r  = (const float*)d_in[10];
    float* out = (float*)d_out;
    float* dom = (float*)d_ws;   // 27 floats of scratch

    domain_branch_kernel<<<1, 128, 0, stream>>>(dn, w1_d, b1_d, w2_d, b2_d, dom);
    jbf_main_kernel<<<NBLK, TPB, 0, stream>>>(guide, x, w1_r, b1_r, w2_r,
                                              b2_r, dom, out);
}

// Round 12
// 52.799 us; speedup vs baseline: 1.4217x; 1.4217x over previous
//
#include <hip/hip_runtime.h>
#include <hip/hip_fp16.h>

// Joint bilateral filter block — 4-wave cooperative, thread-per-patch,
// row-aligned fp16 LDS tile; row-per-thread staging (cvt_pkrtz + 1 b128/row).
// x (1,1,20,96,96) f32; guide_im (N,343) f32, N = 16*96*96 = 147456;
// out n = dd*9216 + h*96 + w uses x depths dd+1..dd+3, H/W zero-pad.
//
// History: r4 52.5 (4 waves, b32 rows); r9 51.4 (b128 rows) = best.
// r5-r8 (8-wave/persistent/reg-prefetch): spill or lockstep. r10 fdot2:
// VGPR-array pressure. r11 (5-wave TPB=320): occupancy collapse to 1 blk/CU.
// This round: r9 conv untouched; staging rewritten row-per-thread
// (3 loads + 4 cvt_pk + 1 ds_write_b128 per 7-float row).

#define NPATCH 147456
#define TPB     256        // 4 waves
#define PPB      64        // patches per block (one per lane, all waves share)
#define NBLK   (NPATCH / PPB)   // 2304
#define ROW_H     8        // halves per row: 7 data + 1 pad (16 B aligned)
#define PATCH_H 392        // 49 rows * 8 halves = 784 B per patch
#define PATCH_D 196        // dwords per patch
#define NROWS  (PPB * 49)  // 3136 rows per tile

typedef float f4u __attribute__((ext_vector_type(4), aligned(4)));
typedef float f2u __attribute__((ext_vector_type(2), aligned(4)));

// ---------------- Kernel A: domain branch (runs once, 1 block) --------------
__global__ __launch_bounds__(128) void domain_branch_kernel(
    const float* __restrict__ dn,
    const float* __restrict__ w1, const float* __restrict__ b1,
    const float* __restrict__ w2, const float* __restrict__ b2,
    float* __restrict__ dom_out)
{
    __shared__ float s_in[344];
    __shared__ float s_c1[128];
    const int t = threadIdx.x;
    for (int idx = t; idx < 343; idx += 128) s_in[idx] = dn[idx];
    __syncthreads();
    if (t < 125) {
        const int i = t / 25, j = (t / 5) % 5, k = t % 5;
        float acc = b1[0];
        const float* base = &s_in[i * 49 + j * 7 + k];
#pragma unroll
        for (int dz = 0; dz < 3; ++dz)
#pragma unroll
            for (int dy = 0; dy < 3; ++dy)
#pragma unroll
                for (int dx = 0; dx < 3; ++dx)
                    acc = fmaf(base[dz * 49 + dy * 7 + dx], w1[dz * 9 + dy * 3 + dx], acc);
        s_c1[t] = fmaxf(acc, 0.f);
    }
    __syncthreads();
    if (t < 27) {
        const int dz = t / 9, dy = (t / 3) % 3, dx = t % 3;
        float acc = b2[0];
#pragma unroll
        for (int u = 0; u < 3; ++u)
#pragma unroll
            for (int v = 0; v < 3; ++v)
#pragma unroll
                for (int q = 0; q < 3; ++q)
                    acc = fmaf(s_c1[(dz + u) * 25 + (dy + v) * 5 + (dx + q)],
                               w2[u * 9 + v * 3 + q], acc);
        dom_out[t] = fmaxf(acc, 0.f);
    }
}

// ---------------- helpers ----------------
__device__ __forceinline__ float h2f_lo(unsigned int q) {
    return __half2float(__ushort_as_half((unsigned short)(q & 0xffffu)));
}
__device__ __forceinline__ float h2f_hi(unsigned int q) {
    return __half2float(__ushort_as_half((unsigned short)(q >> 16)));
}
__device__ __forceinline__ unsigned int pkh(float lo, float hi) {
    return __builtin_bit_cast(unsigned int, __builtin_amdgcn_cvt_pkrtz(lo, hi));
}

// Load row y of absolute z-slice zi (16B-aligned, 8-half rows) into d[0..6].
// One ds_read_b128. zi, y fold to compile-time constants after unrolling.
__device__ __forceinline__ void load_row(const unsigned int* __restrict__ P, float* d,
                                         int zi, int y) {
    const int d0 = zi * 28 + y * 4;        // dword offset, multiple of 4 -> 16B
    const uint4 q = *reinterpret_cast<const uint4*>(P + d0);
    d[0] = h2f_lo(q.x); d[1] = h2f_hi(q.x);
    d[2] = h2f_lo(q.y); d[3] = h2f_hi(q.y);
    d[4] = h2f_lo(q.z); d[5] = h2f_hi(q.z);
    d[6] = h2f_lo(q.w);
}

// Run conv1+fused-conv2 row-tasks (i,j) from (IB,JB) to (IE,JE) inclusive,
// in row-major task order, accumulating into a2 (partial).
template<int IB, int JB, int IE, int JE>
__device__ __forceinline__ void run_tasks(const unsigned int* __restrict__ P,
                                          const float* __restrict__ w1, float bb1,
                                          const float* __restrict__ w2,
                                          float (&a2)[3][3][3])
{
#pragma unroll
    for (int i = IB; i <= IE; ++i) {              // c1 z-slab (input slices i..i+2)
        float rw[3][3][7];                        // [u][y%3][k]
        const int j0 = (i == IB) ? JB : 0;
        const int j1 = (i == IE) ? JE : 4;
#pragma unroll
        for (int j = j0; j <= j1; ++j) {
            if (j == j0) {
#pragma unroll
                for (int u = 0; u < 3; ++u)
#pragma unroll
                    for (int dy = 0; dy < 3; ++dy)
                        load_row(P, rw[u][(j + dy) % 3], i + u, j + dy);
            } else {
#pragma unroll
                for (int u = 0; u < 3; ++u)
                    load_row(P, rw[u][(j + 2) % 3], i + u, j + 2);
            }

            // c1 row (i, j, k=0..4)
            float c1r[5];
#pragma unroll
            for (int k = 0; k < 5; ++k) {
                float a = bb1;
#pragma unroll
                for (int u = 0; u < 3; ++u)
#pragma unroll
                    for (int v = 0; v < 3; ++v) {
                        const float* rr = rw[u][(j + v) % 3];
#pragma unroll
                        for (int w = 0; w < 3; ++w)
                            a = fmaf(rr[k + w], w1[u * 9 + v * 3 + w], a);
                    }
                c1r[k] = fmaxf(a, 0.f);
            }

            // fused conv2 accumulation
#pragma unroll
            for (int dz2 = 0; dz2 < 3; ++dz2) {
                const int u2 = i - dz2;
                if (u2 >= 0 && u2 < 3) {
#pragma unroll
                    for (int v2 = 0; v2 < 3; ++v2) {
                        const int dy2 = j - v2;
                        if (dy2 >= 0 && dy2 < 3) {
#pragma unroll
                            for (int dx2 = 0; dx2 < 3; ++dx2)
#pragma unroll
                                for (int q = 0; q < 3; ++q)
                                    a2[dz2][dy2][dx2] =
                                        fmaf(c1r[dx2 + q],
                                             w2[u2 * 9 + v2 * 3 + q],
                                             a2[dz2][dy2][dx2]);
                        }
                    }
                }
            }
        }
    }
}

// ---------------- Kernel B: range branch + bilateral combine ----------------
__global__ __launch_bounds__(TPB, 2) void jbf_main_kernel(
    const float* __restrict__ guide, const float* __restrict__ x,
    const float* __restrict__ w1, const float* __restrict__ b1,
    const float* __restrict__ w2, const float* __restrict__ b2,
    const float* __restrict__ dom, float* __restrict__ out)
{
    // partials buffer aliases the (dead-by-then) patch tile: 50,176 B total
    union SM {
        unsigned short tile[PPB * PATCH_H];   // 50,176 B
        float part[3][PPB][27];               // 20,736 B
    };
    __shared__ SM sm;

    const int tid  = threadIdx.x;
    const int wid  = tid >> 6;      // wave 0..3
    const int lane = tid & 63;      // patch owned by this thread
    const int blk  = blockIdx.x;

    // ============== stage 64 patches -> fp16 LDS, row-per-thread ===========
    // row idx: p = idx/49, r = idx%49; src = guide_blk + p*343 + r*7 (7 f32);
    // dst dword = p*196 + r*4 (16B aligned) -> one ds_write_b128.
    {
        const float* __restrict__ srcf = guide + (size_t)blk * (PPB * 343);
        unsigned int* __restrict__ tdw = reinterpret_cast<unsigned int*>(sm.tile);

        int idx = tid;
        int cp = idx / 49, cr = idx - cp * 49;
        f4u a = *reinterpret_cast<const f4u*>(srcf + cp * 343 + cr * 7);
        f2u b = *reinterpret_cast<const f2u*>(srcf + cp * 343 + cr * 7 + 4);
        float c = srcf[cp * 343 + cr * 7 + 6];

#pragma unroll 1
        for (int rd = 0; rd < 12; ++rd) {          // stores rounds 0..11 (full)
            int nidx = idx + TPB;
            if (nidx > NROWS - 1) nidx = NROWS - 1;    // clamp (dup load, rd==11)
            const int np = nidx / 49, nr = nidx - np * 49;
            const float* s = srcf + np * 343 + nr * 7;
            f4u na = *reinterpret_cast<const f4u*>(s);
            f2u nb = *reinterpret_cast<const f2u*>(s + 4);
            float nc = s[6];

            uint4 q;
            q.x = pkh(a.x, a.y); q.y = pkh(a.z, a.w);
            q.z = pkh(b.x, b.y); q.w = pkh(c, 0.f);
            *reinterpret_cast<uint4*>(tdw + cp * PATCH_D + cr * 4) = q;

            idx = nidx; cp = np; cr = nr; a = na; b = nb; c = nc;
        }
        if (tid < NROWS - 12 * TPB) {              // round 12 partial: 64 rows
            uint4 q;
            q.x = pkh(a.x, a.y); q.y = pkh(a.z, a.w);
            q.z = pkh(b.x, b.y); q.w = pkh(c, 0.f);
            *reinterpret_cast<uint4*>(tdw + cp * PATCH_D + cr * 4) = q;
        }
    }
    __syncthreads();

    // ===================== per-thread conv1+conv2 (4-way task split) ========
    const unsigned int* __restrict__ P =
        reinterpret_cast<const unsigned int*>(sm.tile) + lane * PATCH_D;
    const float bb1 = b1[0];

    float a2[3][3][3];
    {
        const float init = (wid == 0) ? b2[0] : 0.f;   // bias added exactly once
#pragma unroll
        for (int a = 0; a < 3; ++a)
#pragma unroll
            for (int b = 0; b < 3; ++b)
#pragma unroll
                for (int c = 0; c < 3; ++c) a2[a][b][c] = init;
    }

    if      (wid == 0) run_tasks<0, 0, 1, 1>(P, w1, bb1, w2, a2);  // 7 tasks
    else if (wid == 1) run_tasks<1, 2, 2, 3>(P, w1, bb1, w2, a2);  // 7 tasks
    else if (wid == 2) run_tasks<2, 4, 3, 4>(P, w1, bb1, w2, a2);  // 6 tasks
    else               run_tasks<4, 0, 4, 4>(P, w1, bb1, w2, a2);  // 5 tasks

    __syncthreads();     // all tile reads complete before aliasing as `part`

    if (wid != 0) {
#pragma unroll
        for (int t = 0; t < 27; ++t)
            sm.part[wid - 1][lane][t] = a2[t / 9][(t / 3) % 3][t % 3];
    }
    __syncthreads();

    // ===================== combine + bilateral (wave 0 only) ================
    if (wid == 0) {
        const int n   = blk * PPB + lane;
        const int dd  = n / 9216;
        const int rem = n - dd * 9216;
        const int h   = rem / 96;
        const int w_  = rem - h * 96;

        float num = 0.f, den = 0.f;
#pragma unroll
        for (int dz = 0; dz < 3; ++dz)
#pragma unroll
            for (int dy = 0; dy < 3; ++dy)
#pragma unroll
                for (int dx = 0; dx < 3; ++dx) {
                    const int t = dz * 9 + dy * 3 + dx;
                    const float r2 = fmaxf(a2[dz][dy][dx] + sm.part[0][lane][t]
                                           + sm.part[1][lane][t]
                                           + sm.part[2][lane][t], 0.f);
                    const float wt = fmaf(dom[t], r2, 1e-10f);
                    const int yy = h - 1 + dy, xx = w_ - 1 + dx;
                    float xv = 0.f;
                    if (yy >= 0 && yy < 96 && xx >= 0 && xx < 96)
                        xv = x[(dd + 1 + dz) * 9216 + yy * 96 + xx];
                    num = fmaf(wt, xv, num);
                    den += wt;
                }
        out[n] = num / den;
    }
}

extern "C" void kernel_launch(void* const* d_in, const int* in_sizes, int n_in,
                              void* d_out, int out_size, void* d_ws, size_t ws_size,
                              hipStream_t stream) {
    const float* x     = (const float*)d_in[0];
    const float* dn    = (const float*)d_in[1];
    const float* guide = (const float*)d_in[2];
    const float* w1_d  = (const float*)d_in[3];
    const float* b1_d  = (const float*)d_in[4];
    const float* w2_d  = (const float*)d_in[5];
    const float* b2_d  = (const float*)d_in[6];
    const float* w1_r  = (const float*)d_in[7];
    const float* b1_r  = (const float*)d_in[8];
    const float* w2_r  = (const float*)d_in[9];
    const float* b2_r  = (const float*)d_in[10];
    float* out = (float*)d_out;
    float* dom = (float*)d_ws;   // 27 floats of scratch

    domain_branch_kernel<<<1, 128, 0, stream>>>(dn, w1_d, b1_d, w2_d, b2_d, dom);
    jbf_main_kernel<<<NBLK, TPB, 0, stream>>>(guide, x, w1_r, b1_r, w2_r,
                                              b2_r, dom, out);
}